// Round 9
// baseline (199.668 us; speedup 1.0000x reference)
//
#include <hip/hip_runtime.h>

// Problem constants
#define BB   4
#define SEQ  2048
#define EMB  512
#define NH   8
#define HD   64
// SCALE = HD^-0.5 = 0.125; folded with log2(e) into Q at qkv epilogue:
#define QSCALE 0.18033688011f   // 0.125 * log2(e)

typedef __bf16 bf16x8 __attribute__((ext_vector_type(8)));
typedef float  f32x4  __attribute__((ext_vector_type(4)));

__device__ __forceinline__ short f2bf(float f) {
  union { float f; unsigned u; } v; v.f = f;
  unsigned r = v.u + 0x7fffu + ((v.u >> 16) & 1u);   // RNE
  return (short)(r >> 16);
}

// packed fp32x2 -> bf16x2 (RNE), hardware on gfx950
__device__ __forceinline__ unsigned pk_bf16(float a, float b) {
#if __has_builtin(__builtin_amdgcn_cvt_pk_bf16_f32)
  typedef __bf16 bf16v2 __attribute__((ext_vector_type(2)));
  union { bf16v2 v; unsigned u; } cv;
  cv.v = __builtin_amdgcn_cvt_pk_bf16_f32(a, b);
  return cv.u;
#else
  return (unsigned)(unsigned short)f2bf(a) | ((unsigned)(unsigned short)f2bf(b) << 16);
#endif
}

__device__ __forceinline__ float fexp2(float x) {
#if __has_builtin(__builtin_amdgcn_exp2f)
  return __builtin_amdgcn_exp2f(x);
#else
  return exp2f(x);
#endif
}

__device__ __forceinline__ void gl_lds16(const void* g, void* l) {
  __builtin_amdgcn_global_load_lds(
      (const __attribute__((address_space(1))) unsigned int*)g,
      (__attribute__((address_space(3))) unsigned int*)l, 16, 0, 0);
}

// quad-axis redistribution for P: (a,b) = (even-kt, odd-kt) packed pair.
// After the two swaps (gfx950 VALU cross-lane, no LDS pipe) the words land in
// exactly the PV A-fragment layout (verified round 4: absmax unchanged, conflicts 0).
__device__ __forceinline__ void quad_redist(unsigned &a, unsigned &b) {
  asm volatile("v_permlane32_swap_b32 %0, %1" : "+v"(a), "+v"(b));
  asm volatile("v_permlane16_swap_b32 %0, %1" : "+v"(a), "+v"(b));
}

// cast a float4-pair (8 consecutive f32) to 16B of bf16 (uint4)
__device__ __forceinline__ uint4 cast8(const float4 a, const float4 b) {
  uint4 w;
  w.x = pk_bf16(a.x, a.y); w.y = pk_bf16(a.z, a.w);
  w.z = pk_bf16(b.x, b.y); w.w = pk_bf16(b.z, b.w);
  return w;
}

// ---------------------------------------------------------------- QKV projection (f32 inputs, fused cast)
// C[m,f] = sum_e x[m,e]*Wqkv[f,e] + b[f]; Q gets *QSCALE; scatter Q,K (b,h,n,d), V^T (b,h,d,n)
// v3: reads x and w_qkv as f32 DIRECTLY (cast_all eliminated — 4->3 kernels).
//   Staging = reg-staged cast: load float4s for step t+1 EARLY, compute(t) hides
//   the latency, then cvt_pk + ds_write_b128 late; one barrier per K-step (T14).
// BK=32 double-buffered; swizzle: store chunk c of row holds k-chunk c^((row>>1)&3);
//   read chunk quad^((col>>1)&3) recovers source chunk quad (row base mult of 16).
__global__ __launch_bounds__(256) void qkv_gemm(const float* __restrict__ X,
                                                const float* __restrict__ W,
                                                const float* __restrict__ bias,
                                                short* __restrict__ qo,
                                                short* __restrict__ ko,
                                                short* __restrict__ vto) {
  __shared__ __align__(16) short As0[128 * 32];
  __shared__ __align__(16) short Bs0[128 * 32];
  __shared__ __align__(16) short As1[128 * 32];
  __shared__ __align__(16) short Bs1[128 * 32];
  const int tid  = threadIdx.x;
  const int lane = tid & 63, wave = tid >> 6;
  const int wm = wave >> 1, wf = wave & 1;
  const int col = lane & 15, quad = lane >> 4;
  const int m0 = blockIdx.x * 128, f0 = blockIdx.y * 128;

  // staging source base pointers (f32): slot = rd*256+tid, row = slot>>2,
  // chunk = slot&3, source k-chunk cb = (slot&3)^((slot>>3)&3)
  const float* aS[2]; const float* wS[2];
  int dstOff[2];
#pragma unroll
  for (int rd = 0; rd < 2; ++rd) {
    int slot = rd * 256 + tid;
    int row  = slot >> 2;
    int cb   = (slot & 3) ^ ((slot >> 3) & 3);
    aS[rd] = X + (size_t)(m0 + row) * 512 + cb * 8;
    wS[rd] = W + (size_t)(f0 + row) * 512 + cb * 8;
    dstOff[rd] = slot * 16;          // byte offset in the 8KB LDS buffer
  }
  // fragment LDS element offsets (row*32 + readchunk*8)
  int aOff[4], bOff[4];
  const int rc = (quad ^ ((col >> 1) & 3)) * 8;
#pragma unroll
  for (int i = 0; i < 4; ++i) {
    aOff[i] = (wm * 64 + i * 16 + col) * 32 + rc;
    bOff[i] = (wf * 64 + i * 16 + col) * 32 + rc;
  }

  f32x4 acc[4][4];
#pragma unroll
  for (int i = 0; i < 4; ++i)
#pragma unroll
    for (int j = 0; j < 4; ++j)
#pragma unroll
      for (int r = 0; r < 4; ++r) acc[i][j][r] = 0.f;

  float4 ra[2][2], rw[2][2];       // in-flight staging registers (32 VGPR)

#define QLOAD(KS)                                                       \
  {                                                                     \
    const int ko_ = (KS) * 32;                                          \
    _Pragma("unroll")                                                   \
    for (int rd = 0; rd < 2; ++rd) {                                    \
      ra[rd][0] = *(const float4*)(aS[rd] + ko_);                       \
      ra[rd][1] = *(const float4*)(aS[rd] + ko_ + 4);                   \
      rw[rd][0] = *(const float4*)(wS[rd] + ko_);                       \
      rw[rd][1] = *(const float4*)(wS[rd] + ko_ + 4);                   \
    }                                                                   \
  }
#define QWRITE(BUFA, BUFB)                                              \
  {                                                                     \
    _Pragma("unroll")                                                   \
    for (int rd = 0; rd < 2; ++rd) {                                    \
      *(uint4*)((char*)(BUFA) + dstOff[rd]) = cast8(ra[rd][0], ra[rd][1]); \
      *(uint4*)((char*)(BUFB) + dstOff[rd]) = cast8(rw[rd][0], rw[rd][1]); \
    }                                                                   \
  }

  auto qcompute = [&](const short* As, const short* Bs) {
    bf16x8 af[4], bw[4];
#pragma unroll
    for (int i = 0; i < 4; ++i) af[i] = *(const bf16x8*)&As[aOff[i]];
#pragma unroll
    for (int j = 0; j < 4; ++j) bw[j] = *(const bf16x8*)&Bs[bOff[j]];
#pragma unroll
    for (int i = 0; i < 4; ++i)
#pragma unroll
      for (int j = 0; j < 4; ++j)
        acc[i][j] = __builtin_amdgcn_mfma_f32_16x16x32_bf16(af[i], bw[j], acc[i][j], 0, 0, 0);
  };

  // prologue: stage step 0
  QLOAD(0); QWRITE(As0, Bs0);
  __syncthreads();
  for (int t = 0; t < 16; t += 2) {
    QLOAD(t + 1);                    // issue early — compute hides the latency
    qcompute(As0, Bs0);
    QWRITE(As1, Bs1);                // write-late into the idle buffer
    __syncthreads();
    QLOAD((t + 2) & 15);             // last iter wraps to 0 (harmless, avoids OOB)
    qcompute(As1, Bs1);
    QWRITE(As0, Bs0);
    __syncthreads();
  }
#undef QLOAD
#undef QWRITE

  // epilogue: C/D layout row = quad*4+r, col = lane&15
#pragma unroll
  for (int j = 0; j < 4; ++j) {
    const int f = f0 + wf * 64 + j * 16 + col;
    const float bv = bias[f];
    const int sIdx = f >> 9;          // 0=Q 1=K 2=V (wave-uniform)
    const int h = (f >> 6) & 7;
    const int d = f & 63;
#pragma unroll
    for (int i = 0; i < 4; ++i) {
      const int mbase = m0 + wm * 64 + i * 16 + quad * 4;
      const int b = mbase >> 11;
      const int n = mbase & 2047;
      const size_t bh = (size_t)(b * NH + h);
      if (sIdx == 2) {
        uint2 pk;
        pk.x = pk_bf16(acc[i][j][0] + bv, acc[i][j][1] + bv);
        pk.y = pk_bf16(acc[i][j][2] + bv, acc[i][j][3] + bv);
        *(uint2*)&vto[(bh * HD + d) * SEQ + n] = pk;     // V^T: (bh, d, n)
      } else if (sIdx == 0) {
#pragma unroll
        for (int r = 0; r < 4; ++r)
          qo[(bh * SEQ + n + r) * HD + d] = f2bf((acc[i][j][r] + bv) * QSCALE);
      } else {
#pragma unroll
        for (int r = 0; r < 4; ++r)
          ko[(bh * SEQ + n + r) * HD + d] = f2bf(acc[i][j][r] + bv);
      }
    }
  }
}

// ---------------------------------------------------------------- flash attention v7 (round-4/8 best: 55.7us)
// grid = 512 x 512 threads: bh = blk&31, qtile = blk>>5 (128 q/block, 8 waves x 16 q)
// K,V: double-buffered LDS (XOR-swizzled, global_load_lds), 1 barrier/tile.
// P: in-register redistribution (permlane16/32_swap), no LDS round-trip.
// S^T operand-swap; fixed-max softmax (exp2, scale pre-folded into Q).
__global__ __launch_bounds__(512) void attn_kernel(const short* __restrict__ q,
                                                   const short* __restrict__ k,
                                                   const short* __restrict__ vt,
                                                   short* __restrict__ o) {
  __shared__ __align__(16) short Ks0[64 * 64];       // XOR-swizzled
  __shared__ __align__(16) short Vs0[64 * 64];
  __shared__ __align__(16) short Ks1[64 * 64];
  __shared__ __align__(16) short Vs1[64 * 64];

  const int tid  = threadIdx.x;
  const int lane = tid & 63, wave = tid >> 6;
  const int col = lane & 15, quad = lane >> 4;
  const int bh = blockIdx.x & 31;
  const int q0 = (blockIdx.x >> 5) * 128;
  const size_t bhBase = (size_t)bh * SEQ * HD;

  // Q fragments (B-operand): lane holds Q'[q=col][d = ks*32 + quad*8 + j]
  bf16x8 qf[2];
#pragma unroll
  for (int ks = 0; ks < 2; ++ks)
    qf[ks] = *(const bf16x8*)&q[bhBase +
        (size_t)(q0 + wave * 16 + col) * HD + ks * 32 + quad * 8];

  // staging: 512 threads x 16B = one 64x64 bf16 tile per issue
  const int row = tid >> 3, cb = (tid & 7) ^ (row & 7);
  const short* ksrc = k  + bhBase + (size_t)row * HD  + cb * 8;
  const short* vsrc = vt + bhBase + (size_t)row * SEQ + cb * 8;
  char* const ldsK0 = (char*)Ks0 + wave * 1024;
  char* const ldsV0 = (char*)Vs0 + wave * 1024;
  char* const ldsK1 = (char*)Ks1 + wave * 1024;
  char* const ldsV1 = (char*)Vs1 + wave * 1024;

  f32x4 oacc[4];
#pragma unroll
  for (int nt = 0; nt < 4; ++nt)
#pragma unroll
    for (int r = 0; r < 4; ++r) oacc[nt][r] = 0.f;
  float lsum = 0.f;

  auto compute = [&](const short* KB, const short* VB) {
    // S^T = K Q'^T : C[m=key][n=q]; lane holds S^T[key=kt*16+quad*4+r][q=col]
    f32x4 sacc[4];
#pragma unroll
    for (int kt = 0; kt < 4; ++kt)
#pragma unroll
      for (int r = 0; r < 4; ++r) sacc[kt][r] = 0.f;
#pragma unroll
    for (int ks = 0; ks < 2; ++ks)
#pragma unroll
      for (int kt = 0; kt < 4; ++kt) {
        bf16x8 kf = *(const bf16x8*)&KB[(kt * 16 + col) * 64 +
                                        (((ks * 4 + quad) ^ (col & 7)) * 8)];
        sacc[kt] = __builtin_amdgcn_mfma_f32_16x16x32_bf16(kf, qf[ks], sacc[kt], 0, 0, 0);
      }

    // p = exp2(s') (scale pre-folded into Q'), partial row-sums, pack pairs
    unsigned u[4][2];
#pragma unroll
    for (int kt = 0; kt < 4; ++kt) {
      float p0 = fexp2(sacc[kt][0]);
      float p1 = fexp2(sacc[kt][1]);
      float p2 = fexp2(sacc[kt][2]);
      float p3 = fexp2(sacc[kt][3]);
      lsum += (p0 + p1) + (p2 + p3);
      u[kt][0] = pk_bf16(p0, p1);   // keys kt*16+quad*4+{0,1}
      u[kt][1] = pk_bf16(p2, p3);   // keys kt*16+quad*4+{2,3}
    }

    // in-register quad redistribution -> PV A-fragments
    // pf[ks2] elem j = P[q=col][key = ks2*32 + quad*8 + j]
    union { unsigned w[4]; bf16x8 v; } pf0, pf1;
    {
      unsigned a, b;
      a = u[0][0]; b = u[1][0]; quad_redist(a, b); pf0.w[0] = a; pf0.w[2] = b;
      a = u[0][1]; b = u[1][1]; quad_redist(a, b); pf0.w[1] = a; pf0.w[3] = b;
      a = u[2][0]; b = u[3][0]; quad_redist(a, b); pf1.w[0] = a; pf1.w[2] = b;
      a = u[2][1]; b = u[3][1]; quad_redist(a, b); pf1.w[1] = a; pf1.w[3] = b;
    }

    // O += P V   (A = P[q][key] in registers, B = V^T[d][key] from LDS)
#pragma unroll
    for (int nt = 0; nt < 4; ++nt) {
      bf16x8 vf0 = *(const bf16x8*)&VB[(nt * 16 + col) * 64 +
                                       ((quad ^ (col & 7)) * 8)];
      oacc[nt] = __builtin_amdgcn_mfma_f32_16x16x32_bf16(pf0.v, vf0, oacc[nt], 0, 0, 0);
      bf16x8 vf1 = *(const bf16x8*)&VB[(nt * 16 + col) * 64 +
                                       (((4 + quad) ^ (col & 7)) * 8)];
      oacc[nt] = __builtin_amdgcn_mfma_f32_16x16x32_bf16(pf1.v, vf1, oacc[nt], 0, 0, 0);
    }
  };

  // prologue: stage tile 0
  gl_lds16(ksrc, ldsK0); gl_lds16(vsrc, ldsV0);
  ksrc += 64 * HD; vsrc += 64;
  __syncthreads();

  for (int t = 0; t < 32; t += 2) {
    // stage tile t+1 into buf1; compute tile t from buf0
    gl_lds16(ksrc, ldsK1); gl_lds16(vsrc, ldsV1);
    ksrc += 64 * HD; vsrc += 64;
    compute(Ks0, Vs0);
    __syncthreads();                 // drains t+1 loads (flew during compute)
    // stage tile t+2 into buf0; compute tile t+1 from buf1
    // (final iteration prefetches one tile past the end — lands in the
    //  adjacent workspace arrays, in-bounds of d_ws, never consumed)
    gl_lds16(ksrc, ldsK0); gl_lds16(vsrc, ldsV0);
    ksrc += 64 * HD; vsrc += 64;
    compute(Ks1, Vs1);
    __syncthreads();
  }

  // final row-sum reduce across quads (lanes sharing col hold partials)
  lsum += __shfl_xor(lsum, 16);
  lsum += __shfl_xor(lsum, 32);

  const int b = bh >> 3, h = bh & 7;
#pragma unroll
  for (int r = 0; r < 4; ++r) {
    const float rl = 1.0f / __shfl(lsum, quad * 4 + r);  // sum for q=quad*4+r lives at lane col==q
    const int n = q0 + wave * 16 + quad * 4 + r;
#pragma unroll
    for (int nt = 0; nt < 4; ++nt)
      o[((size_t)(b * SEQ + n)) * EMB + h * HD + nt * 16 + col] = f2bf(oacc[nt][r] * rl);
  }
}

// ---------------------------------------------------------------- out projection (f32 weights, fused cast)
// v3: W read as f32 directly (reg-staged cast, load-early/write-late);
//   A (= attn output ob, bf16) stays global_load_lds. BK=32 dbuf, 1 barrier/step.
// 64x128 tiles.  out[m,f] = sum_e o[m,e]*Wout[f,e] + b[f]
__global__ __launch_bounds__(256) void proj_gemm(const short* __restrict__ A,
                                                 const float* __restrict__ W,
                                                 const float* __restrict__ bias,
                                                 float* __restrict__ out) {
  __shared__ __align__(16) short As0[64 * 32];
  __shared__ __align__(16) short Bs0[128 * 32];
  __shared__ __align__(16) short As1[64 * 32];
  __shared__ __align__(16) short Bs1[128 * 32];
  const int tid  = threadIdx.x;
  const int lane = tid & 63, wave = tid >> 6;
  const int wm = wave >> 1, wf = wave & 1;
  const int col = lane & 15, quad = lane >> 4;
  const int m0 = blockIdx.x * 64, f0 = blockIdx.y * 128;

  // A: one gl_lds16 issue (64 rows of bf16 ob)
  const short* aSrcP;
  {
    int row = tid >> 2;
    int cb  = (tid & 3) ^ ((tid >> 3) & 3);
    aSrcP = A + (size_t)(m0 + row) * 512 + cb * 8;
  }
  // W: two reg-staged f32 slots (128 rows)
  const float* wS[2];
  int dstOff[2];
#pragma unroll
  for (int rd = 0; rd < 2; ++rd) {
    int slot = rd * 256 + tid;
    int row  = slot >> 2;
    int cb   = (slot & 3) ^ ((slot >> 3) & 3);
    wS[rd] = W + (size_t)(f0 + row) * 512 + cb * 8;
    dstOff[rd] = slot * 16;
  }
  int aOff[2], bOff[4];
  const int rc = (quad ^ ((col >> 1) & 3)) * 8;
#pragma unroll
  for (int i = 0; i < 2; ++i)
    aOff[i] = (wm * 32 + i * 16 + col) * 32 + rc;
#pragma unroll
  for (int j = 0; j < 4; ++j)
    bOff[j] = (wf * 64 + j * 16 + col) * 32 + rc;

  f32x4 acc[2][4];
#pragma unroll
  for (int i = 0; i < 2; ++i)
#pragma unroll
    for (int j = 0; j < 4; ++j)
#pragma unroll
      for (int r = 0; r < 4; ++r) acc[i][j][r] = 0.f;

  float4 rw[2][2];

#define PLOADW(KS)                                                      \
  {                                                                     \
    const int ko_ = (KS) * 32;                                          \
    _Pragma("unroll")                                                   \
    for (int rd = 0; rd < 2; ++rd) {                                    \
      rw[rd][0] = *(const float4*)(wS[rd] + ko_);                       \
      rw[rd][1] = *(const float4*)(wS[rd] + ko_ + 4);                   \
    }                                                                   \
  }
#define PWRITEW(BUFB)                                                   \
  {                                                                     \
    _Pragma("unroll")                                                   \
    for (int rd = 0; rd < 2; ++rd)                                      \
      *(uint4*)((char*)(BUFB) + dstOff[rd]) = cast8(rw[rd][0], rw[rd][1]); \
  }
#define PLOADA(BUFA, KS)                                                \
    gl_lds16(aSrcP + (KS) * 32, (char*)(BUFA) + wave * 1024);

  auto pcompute = [&](const short* As, const short* Bs) {
    bf16x8 af[2], bw[4];
#pragma unroll
    for (int i = 0; i < 2; ++i) af[i] = *(const bf16x8*)&As[aOff[i]];
#pragma unroll
    for (int j = 0; j < 4; ++j) bw[j] = *(const bf16x8*)&Bs[bOff[j]];
#pragma unroll
    for (int i = 0; i < 2; ++i)
#pragma unroll
      for (int j = 0; j < 4; ++j)
        acc[i][j] = __builtin_amdgcn_mfma_f32_16x16x32_bf16(af[i], bw[j], acc[i][j], 0, 0, 0);
  };

  // prologue
  PLOADW(0); PWRITEW(Bs0); PLOADA(As0, 0);
  __syncthreads();
  for (int t = 0; t < 16; t += 2) {
    PLOADA(As1, t + 1);
    PLOADW(t + 1);
    pcompute(As0, Bs0);
    PWRITEW(Bs1);
    __syncthreads();                 // drains As1 gl_lds + publishes Bs1
    PLOADA(As0, (t + 2) & 15);       // wrap on last iter (harmless, avoids OOB)
    PLOADW((t + 2) & 15);
    pcompute(As1, Bs1);
    PWRITEW(Bs0);
    __syncthreads();
  }
#undef PLOADW
#undef PWRITEW
#undef PLOADA

#pragma unroll
  for (int j = 0; j < 4; ++j) {
    const int f = f0 + wf * 64 + j * 16 + col;
    const float bv = bias[f];
#pragma unroll
    for (int i = 0; i < 2; ++i) {
      const int mbase = m0 + wm * 32 + i * 16 + quad * 4;
#pragma unroll
      for (int r = 0; r < 4; ++r)
        out[(size_t)(mbase + r) * 512 + f] = acc[i][j][r] + bv;
    }
  }
}

// ---------------------------------------------------------------- launch (3 kernels; cast_all fused away)
extern "C" void kernel_launch(void* const* d_in, const int* in_sizes, int n_in,
                              void* d_out, int out_size, void* d_ws, size_t ws_size,
                              hipStream_t stream) {
  (void)in_sizes; (void)n_in; (void)out_size; (void)ws_size;
  const float* x     = (const float*)d_in[0];
  const float* w_qkv = (const float*)d_in[1];
  const float* b_qkv = (const float*)d_in[2];
  const float* w_out = (const float*)d_in[3];
  const float* b_out = (const float*)d_in[4];
  float* out = (float*)d_out;

  char* ws = (char*)d_ws;
  short* qb  = (short*)(ws + 0);         // 8,388,608  (b,h,n,d)  pre-scaled by QSCALE
  short* kb  = (short*)(ws + 8388608);   // 8,388,608  (b,h,n,d)
  short* vtb = (short*)(ws + 16777216);  // 8,388,608  (b,h,d,n)
  short* ob  = (short*)(ws + 25165824);  // 8,388,608  (b,n,e)

  qkv_gemm<<<dim3(64, 12), 256, 0, stream>>>(x, w_qkv, b_qkv, qb, kb, vtb);
  attn_kernel<<<512, 512, 0, stream>>>(qb, kb, vtb, ob);
  proj_gemm<<<dim3(128, 4), 256, 0, stream>>>(ob, w_out, b_out, out);
}

// Round 10
// 153.769 us; speedup vs baseline: 1.2985x; 1.2985x over previous
//
#include <hip/hip_runtime.h>

// Problem constants
#define BB   4
#define SEQ  2048
#define EMB  512
#define NH   8
#define HD   64
// SCALE = HD^-0.5 = 0.125; folded with log2(e) into Q at qkv epilogue:
#define QSCALE 0.18033688011f   // 0.125 * log2(e)

typedef __bf16 bf16x8 __attribute__((ext_vector_type(8)));
typedef float  f32x4  __attribute__((ext_vector_type(4)));

__device__ __forceinline__ short f2bf(float f) {
  union { float f; unsigned u; } v; v.f = f;
  unsigned r = v.u + 0x7fffu + ((v.u >> 16) & 1u);   // RNE
  return (short)(r >> 16);
}

// packed fp32x2 -> bf16x2 (RNE), hardware on gfx950
__device__ __forceinline__ unsigned pk_bf16(float a, float b) {
#if __has_builtin(__builtin_amdgcn_cvt_pk_bf16_f32)
  typedef __bf16 bf16v2 __attribute__((ext_vector_type(2)));
  union { bf16v2 v; unsigned u; } cv;
  cv.v = __builtin_amdgcn_cvt_pk_bf16_f32(a, b);
  return cv.u;
#else
  return (unsigned)(unsigned short)f2bf(a) | ((unsigned)(unsigned short)f2bf(b) << 16);
#endif
}

__device__ __forceinline__ float fexp2(float x) {
#if __has_builtin(__builtin_amdgcn_exp2f)
  return __builtin_amdgcn_exp2f(x);
#else
  return exp2f(x);
#endif
}

__device__ __forceinline__ void gl_lds16(const void* g, void* l) {
  __builtin_amdgcn_global_load_lds(
      (const __attribute__((address_space(1))) unsigned int*)g,
      (__attribute__((address_space(3))) unsigned int*)l, 16, 0, 0);
}

// quad-axis redistribution for P: (a,b) = (even-kt, odd-kt) packed pair.
// After the two swaps (gfx950 VALU cross-lane, no LDS pipe) the words land in
// exactly the PV A-fragment layout (verified round 4: absmax unchanged, conflicts 0).
__device__ __forceinline__ void quad_redist(unsigned &a, unsigned &b) {
  asm volatile("v_permlane32_swap_b32 %0, %1" : "+v"(a), "+v"(b));
  asm volatile("v_permlane16_swap_b32 %0, %1" : "+v"(a), "+v"(b));
}

// ---------------------------------------------------------------- fused casts
// x: 1048576 float4 groups; w_qkv: 196608; w_out: 65536. total 1310720 -> 5120 blocks
__global__ __launch_bounds__(256) void cast_all(const float* __restrict__ x,
                                                const float* __restrict__ wq,
                                                const float* __restrict__ wo,
                                                short* __restrict__ xb,
                                                short* __restrict__ wqb,
                                                short* __restrict__ wob) {
  int i = blockIdx.x * 256 + threadIdx.x;
  const float* src; short* dst; int off;
  if (i < 1048576)      { src = x;  dst = xb;  off = i; }
  else if (i < 1245184) { src = wq; dst = wqb; off = i - 1048576; }
  else                  { src = wo; dst = wob; off = i - 1245184; }
  float4 v = ((const float4*)src)[off];
  uint2 o; o.x = pk_bf16(v.x, v.y); o.y = pk_bf16(v.z, v.w);
  *(uint2*)&dst[off * 4] = o;
}

// ---------------------------------------------------------------- QKV projection
// v4: occupancy rebuild per round-9 counters (occ 16%, MfmaUtil 6% — latency-bound).
// 512 threads (8 waves as 4m x 2f, wave tile 32x64, acc[2][4]); 128x128 tile, BK=32
// double-buffered, ONE gl_lds16 per operand per K-step (512thr x 16B = 8KB tile),
// one barrier per step. LDS 32KB; __launch_bounds__(512,6) -> 3 blocks/CU exactly
// (grid 768 = 3x256, no tail) = 24 waves/CU in 3 independent barrier domains.
// Swizzle identical to round-8 passing version: store chunk c of row holds source
// k-chunk c^((row>>1)&3); read chunk quad^((col>>1)&3); read rows = 16k+col so
// (row>>1)&3 == (col>>1)&3 and the read recovers source chunk quad.
__global__ __launch_bounds__(512, 6) void qkv_gemm(const short* __restrict__ A,
                                                   const short* __restrict__ W,
                                                   const float* __restrict__ bias,
                                                   short* __restrict__ qo,
                                                   short* __restrict__ ko,
                                                   short* __restrict__ vto) {
  __shared__ __align__(16) short As0[128 * 32];
  __shared__ __align__(16) short Bs0[128 * 32];
  __shared__ __align__(16) short As1[128 * 32];
  __shared__ __align__(16) short Bs1[128 * 32];
  const int tid  = threadIdx.x;
  const int lane = tid & 63, wave = tid >> 6;
  const int wm = wave >> 1, wf = wave & 1;
  const int col = lane & 15, quad = lane >> 4;
  const int m0 = blockIdx.x * 128, f0 = blockIdx.y * 128;

  // staging: slot = tid (512 slots = 128 rows x 4 chunks)
  const int row = tid >> 2;
  const int cb  = (tid & 3) ^ ((tid >> 3) & 3);
  const short* aSrc = A + (size_t)(m0 + row) * 512 + cb * 8;
  const short* wSrc = W + (size_t)(f0 + row) * 512 + cb * 8;

  // fragment LDS element offsets (row*32 + readchunk*8)
  const int rc = (quad ^ ((col >> 1) & 3)) * 8;
  int aOff[2], bOff[4];
#pragma unroll
  for (int i = 0; i < 2; ++i) aOff[i] = (wm * 32 + i * 16 + col) * 32 + rc;
#pragma unroll
  for (int j = 0; j < 4; ++j) bOff[j] = (wf * 64 + j * 16 + col) * 32 + rc;

  f32x4 acc[2][4];
#pragma unroll
  for (int i = 0; i < 2; ++i)
#pragma unroll
    for (int j = 0; j < 4; ++j)
#pragma unroll
      for (int r = 0; r < 4; ++r) acc[i][j][r] = 0.f;

#define QSTAGE(BUFA, BUFB, KS)                                        \
  {                                                                   \
    gl_lds16(aSrc + (KS) * 32, (char*)(BUFA) + wave * 1024);          \
    gl_lds16(wSrc + (KS) * 32, (char*)(BUFB) + wave * 1024);          \
  }

  auto qcompute = [&](const short* As, const short* Bs) {
    bf16x8 af[2], bw[4];
#pragma unroll
    for (int i = 0; i < 2; ++i) af[i] = *(const bf16x8*)&As[aOff[i]];
#pragma unroll
    for (int j = 0; j < 4; ++j) bw[j] = *(const bf16x8*)&Bs[bOff[j]];
#pragma unroll
    for (int i = 0; i < 2; ++i)
#pragma unroll
      for (int j = 0; j < 4; ++j)
        acc[i][j] = __builtin_amdgcn_mfma_f32_16x16x32_bf16(af[i], bw[j], acc[i][j], 0, 0, 0);
  };

  // prologue
  QSTAGE(As0, Bs0, 0);
  __syncthreads();
  for (int t = 0; t < 16; t += 2) {
    QSTAGE(As1, Bs1, t + 1);          // t+1 <= 15 always
    qcompute(As0, Bs0);
    __syncthreads();                  // drains t+1 loads (flew during compute)
    QSTAGE(As0, Bs0, (t + 2) & 15);   // last iter wraps to 0 (harmless, avoids OOB)
    qcompute(As1, Bs1);
    __syncthreads();
  }
#undef QSTAGE

  // epilogue: C/D layout row = quad*4+r, col = lane&15
#pragma unroll
  for (int j = 0; j < 4; ++j) {
    const int f = f0 + wf * 64 + j * 16 + col;
    const float bv = bias[f];
    const int sIdx = f >> 9;          // 0=Q 1=K 2=V (uniform per wave: 64-wide span)
    const int h = (f >> 6) & 7;
    const int d = f & 63;
#pragma unroll
    for (int i = 0; i < 2; ++i) {
      const int mbase = m0 + wm * 32 + i * 16 + quad * 4;
      const int b = mbase >> 11;
      const int n = mbase & 2047;
      const size_t bh = (size_t)(b * NH + h);
      if (sIdx == 2) {
        uint2 pk;
        pk.x = pk_bf16(acc[i][j][0] + bv, acc[i][j][1] + bv);
        pk.y = pk_bf16(acc[i][j][2] + bv, acc[i][j][3] + bv);
        *(uint2*)&vto[(bh * HD + d) * SEQ + n] = pk;     // V^T: (bh, d, n)
      } else if (sIdx == 0) {
#pragma unroll
        for (int r = 0; r < 4; ++r)
          qo[(bh * SEQ + n + r) * HD + d] = f2bf((acc[i][j][r] + bv) * QSCALE);
      } else {
#pragma unroll
        for (int r = 0; r < 4; ++r)
          ko[(bh * SEQ + n + r) * HD + d] = f2bf(acc[i][j][r] + bv);
      }
    }
  }
}

// ---------------------------------------------------------------- flash attention v7 (round-4/8 best: 55.7us)
// grid = 512 x 512 threads: bh = blk&31, qtile = blk>>5 (128 q/block, 8 waves x 16 q)
// K,V: double-buffered LDS (XOR-swizzled, global_load_lds), 1 barrier/tile.
// P: in-register redistribution (permlane16/32_swap), no LDS round-trip.
// S^T operand-swap; fixed-max softmax (exp2, scale pre-folded into Q).
__global__ __launch_bounds__(512) void attn_kernel(const short* __restrict__ q,
                                                   const short* __restrict__ k,
                                                   const short* __restrict__ vt,
                                                   short* __restrict__ o) {
  __shared__ __align__(16) short Ks0[64 * 64];       // XOR-swizzled
  __shared__ __align__(16) short Vs0[64 * 64];
  __shared__ __align__(16) short Ks1[64 * 64];
  __shared__ __align__(16) short Vs1[64 * 64];

  const int tid  = threadIdx.x;
  const int lane = tid & 63, wave = tid >> 6;
  const int col = lane & 15, quad = lane >> 4;
  const int bh = blockIdx.x & 31;
  const int q0 = (blockIdx.x >> 5) * 128;
  const size_t bhBase = (size_t)bh * SEQ * HD;

  // Q fragments (B-operand): lane holds Q'[q=col][d = ks*32 + quad*8 + j]
  bf16x8 qf[2];
#pragma unroll
  for (int ks = 0; ks < 2; ++ks)
    qf[ks] = *(const bf16x8*)&q[bhBase +
        (size_t)(q0 + wave * 16 + col) * HD + ks * 32 + quad * 8];

  // staging: 512 threads x 16B = one 64x64 bf16 tile per issue
  const int row = tid >> 3, cb = (tid & 7) ^ (row & 7);
  const short* ksrc = k  + bhBase + (size_t)row * HD  + cb * 8;
  const short* vsrc = vt + bhBase + (size_t)row * SEQ + cb * 8;
  char* const ldsK0 = (char*)Ks0 + wave * 1024;
  char* const ldsV0 = (char*)Vs0 + wave * 1024;
  char* const ldsK1 = (char*)Ks1 + wave * 1024;
  char* const ldsV1 = (char*)Vs1 + wave * 1024;

  f32x4 oacc[4];
#pragma unroll
  for (int nt = 0; nt < 4; ++nt)
#pragma unroll
    for (int r = 0; r < 4; ++r) oacc[nt][r] = 0.f;
  float lsum = 0.f;

  auto compute = [&](const short* KB, const short* VB) {
    // S^T = K Q'^T : C[m=key][n=q]; lane holds S^T[key=kt*16+quad*4+r][q=col]
    f32x4 sacc[4];
#pragma unroll
    for (int kt = 0; kt < 4; ++kt)
#pragma unroll
      for (int r = 0; r < 4; ++r) sacc[kt][r] = 0.f;
#pragma unroll
    for (int ks = 0; ks < 2; ++ks)
#pragma unroll
      for (int kt = 0; kt < 4; ++kt) {
        bf16x8 kf = *(const bf16x8*)&KB[(kt * 16 + col) * 64 +
                                        (((ks * 4 + quad) ^ (col & 7)) * 8)];
        sacc[kt] = __builtin_amdgcn_mfma_f32_16x16x32_bf16(kf, qf[ks], sacc[kt], 0, 0, 0);
      }

    // p = exp2(s') (scale pre-folded into Q'), partial row-sums, pack pairs
    unsigned u[4][2];
#pragma unroll
    for (int kt = 0; kt < 4; ++kt) {
      float p0 = fexp2(sacc[kt][0]);
      float p1 = fexp2(sacc[kt][1]);
      float p2 = fexp2(sacc[kt][2]);
      float p3 = fexp2(sacc[kt][3]);
      lsum += (p0 + p1) + (p2 + p3);
      u[kt][0] = pk_bf16(p0, p1);   // keys kt*16+quad*4+{0,1}
      u[kt][1] = pk_bf16(p2, p3);   // keys kt*16+quad*4+{2,3}
    }

    // in-register quad redistribution -> PV A-fragments
    // pf[ks2] elem j = P[q=col][key = ks2*32 + quad*8 + j]
    union { unsigned w[4]; bf16x8 v; } pf0, pf1;
    {
      unsigned a, b;
      a = u[0][0]; b = u[1][0]; quad_redist(a, b); pf0.w[0] = a; pf0.w[2] = b;
      a = u[0][1]; b = u[1][1]; quad_redist(a, b); pf0.w[1] = a; pf0.w[3] = b;
      a = u[2][0]; b = u[3][0]; quad_redist(a, b); pf1.w[0] = a; pf1.w[2] = b;
      a = u[2][1]; b = u[3][1]; quad_redist(a, b); pf1.w[1] = a; pf1.w[3] = b;
    }

    // O += P V   (A = P[q][key] in registers, B = V^T[d][key] from LDS)
#pragma unroll
    for (int nt = 0; nt < 4; ++nt) {
      bf16x8 vf0 = *(const bf16x8*)&VB[(nt * 16 + col) * 64 +
                                       ((quad ^ (col & 7)) * 8)];
      oacc[nt] = __builtin_amdgcn_mfma_f32_16x16x32_bf16(pf0.v, vf0, oacc[nt], 0, 0, 0);
      bf16x8 vf1 = *(const bf16x8*)&VB[(nt * 16 + col) * 64 +
                                       (((4 + quad) ^ (col & 7)) * 8)];
      oacc[nt] = __builtin_amdgcn_mfma_f32_16x16x32_bf16(pf1.v, vf1, oacc[nt], 0, 0, 0);
    }
  };

  // prologue: stage tile 0
  gl_lds16(ksrc, ldsK0); gl_lds16(vsrc, ldsV0);
  ksrc += 64 * HD; vsrc += 64;
  __syncthreads();

  for (int t = 0; t < 32; t += 2) {
    // stage tile t+1 into buf1; compute tile t from buf0
    gl_lds16(ksrc, ldsK1); gl_lds16(vsrc, ldsV1);
    ksrc += 64 * HD; vsrc += 64;
    compute(Ks0, Vs0);
    __syncthreads();                 // drains t+1 loads (flew during compute)
    // stage tile t+2 into buf0; compute tile t+1 from buf1
    // (final iteration prefetches one tile past the end — lands in the
    //  adjacent workspace arrays, in-bounds of d_ws, never consumed)
    gl_lds16(ksrc, ldsK0); gl_lds16(vsrc, ldsV0);
    ksrc += 64 * HD; vsrc += 64;
    compute(Ks1, Vs1);
    __syncthreads();
  }

  // final row-sum reduce across quads (lanes sharing col hold partials)
  lsum += __shfl_xor(lsum, 16);
  lsum += __shfl_xor(lsum, 32);

  const int b = bh >> 3, h = bh & 7;
#pragma unroll
  for (int r = 0; r < 4; ++r) {
    const float rl = 1.0f / __shfl(lsum, quad * 4 + r);  // sum for q=quad*4+r lives at lane col==q
    const int n = q0 + wave * 16 + quad * 4 + r;
#pragma unroll
    for (int nt = 0; nt < 4; ++nt)
      o[((size_t)(b * SEQ + n)) * EMB + h * HD + nt * 16 + col] = f2bf(oacc[nt][r] * rl);
  }
}

// ---------------------------------------------------------------- out projection
// v4: occupancy rebuild. 64x128 tile, BK=32 dbuf, 512 threads (8 waves as 2m x 4f,
// wave tile 32x32, acc[2][2]); grid (128,4) = 512 blocks = 2/CU, LDS 24KB.
// A staged by waves 0-3 (64x32 = 4KB), W by all 8 waves (128x32 = 8KB).
__global__ __launch_bounds__(512, 4) void proj_gemm(const short* __restrict__ A,
                                                    const short* __restrict__ W,
                                                    const float* __restrict__ bias,
                                                    float* __restrict__ out) {
  __shared__ __align__(16) short As0[64 * 32];
  __shared__ __align__(16) short Bs0[128 * 32];
  __shared__ __align__(16) short As1[64 * 32];
  __shared__ __align__(16) short Bs1[128 * 32];
  const int tid  = threadIdx.x;
  const int lane = tid & 63, wave = tid >> 6;
  const int wm = wave >> 2, wf = wave & 3;
  const int col = lane & 15, quad = lane >> 4;
  const int m0 = blockIdx.x * 64, f0 = blockIdx.y * 128;

  // A staging slot (waves 0-3 only): aslot = tid&255 -> 64 rows x 4 chunks
  const int aslot = tid & 255;
  const int arow = aslot >> 2, acb = (aslot & 3) ^ ((aslot >> 3) & 3);
  const short* aSrc = A + (size_t)(m0 + arow) * 512 + acb * 8;
  // W staging slot (all 8 waves): 128 rows x 4 chunks
  const int wrow = tid >> 2, wcb = (tid & 3) ^ ((tid >> 3) & 3);
  const short* wSrc = W + (size_t)(f0 + wrow) * 512 + wcb * 8;

  const int rc = (quad ^ ((col >> 1) & 3)) * 8;
  int aOff[2], bOff[2];
#pragma unroll
  for (int i = 0; i < 2; ++i) aOff[i] = (wm * 32 + i * 16 + col) * 32 + rc;
#pragma unroll
  for (int j = 0; j < 2; ++j) bOff[j] = (wf * 32 + j * 16 + col) * 32 + rc;

  f32x4 acc[2][2];
#pragma unroll
  for (int i = 0; i < 2; ++i)
#pragma unroll
    for (int j = 0; j < 2; ++j)
#pragma unroll
      for (int r = 0; r < 4; ++r) acc[i][j][r] = 0.f;

#define PSTAGE(BUFA, BUFB, KS)                                        \
  {                                                                   \
    if (wave < 4) gl_lds16(aSrc + (KS) * 32, (char*)(BUFA) + wave * 1024); \
    gl_lds16(wSrc + (KS) * 32, (char*)(BUFB) + wave * 1024);          \
  }

  auto pcompute = [&](const short* As, const short* Bs) {
    bf16x8 af[2], bw[2];
#pragma unroll
    for (int i = 0; i < 2; ++i) af[i] = *(const bf16x8*)&As[aOff[i]];
#pragma unroll
    for (int j = 0; j < 2; ++j) bw[j] = *(const bf16x8*)&Bs[bOff[j]];
#pragma unroll
    for (int i = 0; i < 2; ++i)
#pragma unroll
      for (int j = 0; j < 2; ++j)
        acc[i][j] = __builtin_amdgcn_mfma_f32_16x16x32_bf16(af[i], bw[j], acc[i][j], 0, 0, 0);
  };

  PSTAGE(As0, Bs0, 0);
  __syncthreads();
  for (int t = 0; t < 16; t += 2) {
    PSTAGE(As1, Bs1, t + 1);
    pcompute(As0, Bs0);
    __syncthreads();
    PSTAGE(As0, Bs0, (t + 2) & 15);   // wrap on last iter (harmless, avoids OOB)
    pcompute(As1, Bs1);
    __syncthreads();
  }
#undef PSTAGE

#pragma unroll
  for (int j = 0; j < 2; ++j) {
    const int f = f0 + wf * 32 + j * 16 + col;
    const float bv = bias[f];
#pragma unroll
    for (int i = 0; i < 2; ++i) {
      const int mbase = m0 + wm * 32 + i * 16 + quad * 4;
#pragma unroll
      for (int r = 0; r < 4; ++r)
        out[(size_t)(mbase + r) * 512 + f] = acc[i][j][r] + bv;
    }
  }
}

// ---------------------------------------------------------------- launch
extern "C" void kernel_launch(void* const* d_in, const int* in_sizes, int n_in,
                              void* d_out, int out_size, void* d_ws, size_t ws_size,
                              hipStream_t stream) {
  (void)in_sizes; (void)n_in; (void)out_size; (void)ws_size;
  const float* x     = (const float*)d_in[0];
  const float* w_qkv = (const float*)d_in[1];
  const float* b_qkv = (const float*)d_in[2];
  const float* w_out = (const float*)d_in[3];
  const float* b_out = (const float*)d_in[4];
  float* out = (float*)d_out;

  char* ws = (char*)d_ws;
  short* xb    = (short*)(ws + 0);         // 8,388,608
  short* wqkvb = (short*)(ws + 8388608);   // 1,572,864
  short* woutb = (short*)(ws + 9961472);   //   524,288
  short* qb    = (short*)(ws + 10485760);  // 8,388,608  (b,h,n,d)  pre-scaled by QSCALE
  short* kb    = (short*)(ws + 18874368);  // 8,388,608  (b,h,n,d)
  short* vtb   = (short*)(ws + 27262976);  // 8,388,608  (b,h,d,n)
  short* ob    = (short*)(ws + 35651584);  // 8,388,608  (b,n,e)

  cast_all<<<5120, 256, 0, stream>>>(x, w_qkv, w_out, xb, wqkvb, woutb);
  qkv_gemm<<<dim3(64, 12), 512, 0, stream>>>(xb, wqkvb, b_qkv, qb, kb, vtb);
  attn_kernel<<<512, 512, 0, stream>>>(qb, kb, vtb, ob);
  proj_gemm<<<dim3(128, 4), 512, 0, stream>>>(ob, woutb, b_out, out);
}